// Round 9
// baseline (47.762 us; speedup 1.0000x reference)
//
#include <hip/hip_runtime.h>

#define TWO_PI 6.2831853071795864769f

// ws layout (bytes):
//   x1   f32[12*6*256] @ 0       (73728)   stage-0 output
//   x2   f32[12*6*256] @ 73728   (73728)   stage-1 output
//   bar  int[16]       @ 147456  (64)      grid-barrier counters (memset/call)
//
// ONE dispatch. Grid = 6 b x 4 e-tiles = 24 blocks x 512 threads; ~96 KB LDS
// => 1 block/CU, 24 <= 256 CUs => all blocks co-resident (structural, no
// capacity gamble). In-kernel grid barrier between stages replaces the 3
// dependent dispatches of r8 (each dispatch cost ~8 us incl. gap + cold-L2
// restart from the harness's 268MB poison fill).
// thread = (dg 0..15, e2 0..31). Dense part streams (P1 + 0.975*P3) tile
// once per stage feeding 12 h-FMAs per element (12x arithmetic intensity).
// Scatter = sparse corrections (val_s - P1[pos]) at last-write-wins winners,
// resolved ONCE per block in an LDS hash, kept in LDS across all 3 stages.

__global__ __launch_bounds__(512) void fused_all(
    const float* __restrict__ P1, const float* __restrict__ P2,
    const float* __restrict__ P3, const float* __restrict__ T4,
    const int* __restrict__ p5, const int* __restrict__ p6,
    const int* __restrict__ p7, const int* __restrict__ p8,
    const float* __restrict__ f1, const float* __restrict__ ph1,
    const float* __restrict__ T11, const float* __restrict__ f2,
    const float* __restrict__ ph2, const float* __restrict__ T14,
    const float* __restrict__ f3, const float* __restrict__ ph3,
    float* __restrict__ x1, float* __restrict__ x2,
    int* __restrict__ bar, float* __restrict__ out, int K)
{
    __shared__ float v[12 * 256];        // 12 KB  current stage input
    __shared__ float ps[16 * 12 * 64];   // 48 KB  per-dgroup partials
    __shared__ float om[12 * 64];        // 3 KB   merged output tile
    __shared__ float mf[3][64];          //        modulation (pre-inverted)
    __shared__ unsigned pk[2048];        // 8 KB   packed (b,c,d,e)
    __shared__ unsigned hmap[2048];      // 8 KB   winner hash (this b)
    __shared__ unsigned wkc[2048];       // 8 KB   winner (d<<16)|(e<<8)|c
    __shared__ float wp1[2048];          // 8 KB   P1 at winner pos
    __shared__ int nwl;

    const int tid = (int)threadIdx.x;
    const int b  = (int)blockIdx.x >> 2;
    const int t  = (int)blockIdx.x & 3;
    const int e0 = t << 6;
    const int e2 = tid & 31;             // float2 lane: e = e0 + 2*e2 (+1)
    const int dg = tid >> 5;             // 0..15, 16 d per group

    // ---- init: pk staging, hash init, v=P2, modulation ----
    for (int k = tid; k < K; k += 512)
        pk[k] = ((unsigned)p5[k] << 24) | ((unsigned)p6[k] << 16) |
                ((unsigned)p7[k] << 8) | (unsigned)p8[k];
    for (int i = tid; i < 2048; i += 512) hmap[i] = 0xFFFFFFFFu;
    for (int i = tid; i < 3072; i += 512)
        v[i] = P2[(((i >> 8) * 6 + b) << 8) | (i & 255)];
    if (tid < 192) {
        int s = tid >> 6, j = tid & 63;
        float fr = (s == 0) ? f1[0]  : (s == 1) ? f2[0]  : f3[0];
        float ph = (s == 0) ? ph1[0] : (s == 1) ? ph2[0] : ph3[0];
        float sn = __sinf((float)(e0 + j) * TWO_PI * fr + ph);
        float mm = sn * sn * 0.1f + 0.95f;
        mf[s][j] = (s == 1) ? mm : 1.0f / mm;   // s0: /m, s1: *m, s2: /m
    }
    if (tid == 0) nwl = 0;
    __syncthreads();

    // ---- hash insert (this b only): last-write-wins = max k per (d,e) ----
    for (int k = tid; k < K; k += 512) {
        unsigned pv = pk[k];
        if ((pv >> 24) != (unsigned)b) continue;
        unsigned key = pv & 0xFFFFu;                 // (d<<8)|e
        unsigned mine = (key << 12) | (unsigned)k;   // k < 4096
        unsigned hh = (key * 2654435761u) >> 21;     // [0,2048)
        for (;;) {
            unsigned prev = atomicCAS(&hmap[hh], 0xFFFFFFFFu, mine);
            if (prev == 0xFFFFFFFFu) break;
            if ((prev >> 12) == key) { atomicMax(&hmap[hh], mine); break; }
            hh = (hh + 1) & 2047u;
        }
    }
    __syncthreads();

    // ---- winner readback -> compact LDS list (kept across stages) ----
    for (int k = tid; k < K; k += 512) {
        unsigned pv = pk[k];
        if ((pv >> 24) != (unsigned)b) continue;
        unsigned key = pv & 0xFFFFu;
        unsigned hh = (key * 2654435761u) >> 21;
        unsigned cur;
        for (;;) {
            cur = hmap[hh];
            if ((cur >> 12) == key) break;
            hh = (hh + 1) & 2047u;
        }
        if ((cur & 0xFFFu) == (unsigned)k) {         // last write wins
            unsigned c = (pv >> 16) & 0xFFu;
            int w = atomicAdd(&nwl, 1);
            wkc[w] = (key << 8) | c;                 // (d<<16)|(e<<8)|c
            wp1[w] = P1[(b << 16) | key];
        }
    }
    __syncthreads();
    const int nw = nwl;

    const float2* P1v = (const float2*)P1 + (b << 15) + (dg << 11) + (e0 >> 1) + e2;
    const float2* P3v = (const float2*)P3 + (b << 15) + (dg << 11) + (e0 >> 1) + e2;

    for (int s = 0; s < 3; ++s) {
        // ---- dense: stream tile once, 12 h accumulators ----
        float2 acc[12];
        #pragma unroll
        for (int h = 0; h < 12; ++h) acc[h] = make_float2(0.f, 0.f);
        #pragma unroll
        for (int dd = 0; dd < 16; ++dd) {
            float2 a = P1v[dd << 7];
            float2 p = P3v[dd << 7];
            float cx = fmaf(p.x, 0.975f, a.x);
            float cy = fmaf(p.y, 0.975f, a.y);
            const int d = (dg << 4) + dd;
            #pragma unroll
            for (int h = 0; h < 12; ++h) {
                float vv = v[(h << 8) | d];          // half-wave-uniform bcast
                acc[h].x = fmaf(vv, cx, acc[h].x);
                acc[h].y = fmaf(vv, cy, acc[h].y);
            }
        }
        #pragma unroll
        for (int h = 0; h < 12; ++h)
            *(float2*)&ps[((dg * 12 + h) << 6) + (e2 << 1)] = acc[h];
        __syncthreads();

        // ---- merge 16 -> 1 ----
        for (int idx = tid; idx < 768; idx += 512) {
            int h = idx >> 6, e = idx & 63;
            float sum = 0.f;
            #pragma unroll
            for (int g = 0; g < 16; ++g) sum += ps[((g * 12 + h) << 6) | e];
            om[idx] = sum;
        }
        __syncthreads();

        // ---- sparse corrections (in-tile winners) ----
        const float* Tt = (s == 0) ? T4 : (s == 1) ? T11 : T14;
        for (int i = tid; i < nw; i += 512) {
            unsigned wc = wkc[i];
            int e_w = (int)((wc >> 8) & 255u);
            if ((unsigned)(e_w - e0) >= 64u) continue;
            int d_w = (int)(wc >> 16);
            float val = Tt[(b << 8) | (wc & 255u)] - wp1[i];
            #pragma unroll
            for (int h = 0; h < 12; ++h)
                atomicAdd(&om[(h << 6) | (e_w - e0)],
                          v[(h << 8) | d_w] * val);
        }
        __syncthreads();

        // ---- modulate + store ----
        float* dst = (s == 0) ? x1 : (s == 1) ? x2 : out;
        for (int idx = tid; idx < 768; idx += 512) {
            int h = idx >> 6, e = idx & 63;
            dst[((h * 6 + b) << 8) | (e0 + e)] = om[idx] * mf[s][e];
        }

        // ---- grid barrier + reload v (not after last stage) ----
        if (s < 2) {
            __threadfence();                          // release our x writes
            __syncthreads();
            if (tid == 0) {
                __hip_atomic_fetch_add(&bar[s], 1, __ATOMIC_ACQ_REL,
                                       __HIP_MEMORY_SCOPE_AGENT);
                while (__hip_atomic_load(&bar[s], __ATOMIC_ACQUIRE,
                                         __HIP_MEMORY_SCOPE_AGENT) < 24) {}
            }
            __syncthreads();
            __threadfence();                          // acquire (inv caches)
            const float* src = (s == 0) ? x1 : x2;
            for (int i = tid; i < 3072; i += 512)
                v[i] = src[(((i >> 8) * 6 + b) << 8) | (i & 255)];
            __syncthreads();
        }
    }
}

extern "C" void kernel_launch(void* const* d_in, const int* in_sizes, int n_in,
                              void* d_out, int out_size, void* d_ws, size_t ws_size,
                              hipStream_t stream)
{
    (void)n_in; (void)out_size; (void)ws_size;
    const float* P1  = (const float*)d_in[0];
    const float* P2  = (const float*)d_in[1];
    const float* P3  = (const float*)d_in[2];
    const float* T4  = (const float*)d_in[3];
    const int*   p5  = (const int*)d_in[4];
    const int*   p6  = (const int*)d_in[5];
    const int*   p7  = (const int*)d_in[6];
    const int*   p8  = (const int*)d_in[7];
    const float* f1  = (const float*)d_in[8];
    const float* ph1 = (const float*)d_in[9];
    const float* T11 = (const float*)d_in[10];
    const float* f2  = (const float*)d_in[11];
    const float* ph2 = (const float*)d_in[12];
    const float* T14 = (const float*)d_in[13];
    const float* f3  = (const float*)d_in[14];
    const float* ph3 = (const float*)d_in[15];
    float* out = (float*)d_out;
    int K = in_sizes[4];

    char* ws = (char*)d_ws;
    float* x1  = (float*)(ws);
    float* x2  = (float*)(ws + 73728);
    int*   bar = (int*)  (ws + 147456);

    // zero the barrier counters every call (captured as a memset node)
    hipMemsetAsync(bar, 0, 64, stream);
    hipLaunchKernelGGL(fused_all, dim3(24), dim3(512), 0, stream,
                       P1, P2, P3, T4, p5, p6, p7, p8,
                       f1, ph1, T11, f2, ph2, T14, f3, ph3,
                       x1, x2, bar, out, K);
}

// Round 10
// 35.183 us; speedup vs baseline: 1.3575x; 1.3575x over previous
//
#include <hip/hip_runtime.h>

#define TWO_PI 6.2831853071795864769f

// ws layout (bytes):
//   x1   f32[12*6*256] @ 0       (73728)   stage-0 output (LLC-coherent path)
//   x2   f32[12*6*256] @ 73728   (73728)   stage-1 output
//   bar  int[16]       @ 147456  (64)      grid-barrier counters (memset/call)
//
// ONE dispatch, 24 blocks x 512 threads (~96 KB LDS => 1 block/CU; 24 <= 256
// CUs => co-residency structural). Grid barrier with NO acquire/release
// fences: r9's ACQUIRE polls emitted buffer_inv sc1 (L2 invalidate) per
// iteration and __threadfence emitted buffer_wbl2 (L2 writeback) -> ~35us of
// cache-maintenance storm + evicted the P1/P3 tiles. Here ALL cross-block
// data goes through RELAXED agent-scope atomics (sc0 sc1: bypass non-coherent
// L1/L2, served by the coherent LLC). Ordering by completion: __syncthreads
// drains vmcnt(0) for all waves' x-stores before tid0 increments bar.
// Bonus: per-XCD L2 keeps each block's P1/P3 tile warm for stages 1/2.

__global__ __launch_bounds__(512) void fused_all(
    const float* __restrict__ P1, const float* __restrict__ P2,
    const float* __restrict__ P3, const float* __restrict__ T4,
    const int* __restrict__ p5, const int* __restrict__ p6,
    const int* __restrict__ p7, const int* __restrict__ p8,
    const float* __restrict__ f1, const float* __restrict__ ph1,
    const float* __restrict__ T11, const float* __restrict__ f2,
    const float* __restrict__ ph2, const float* __restrict__ T14,
    const float* __restrict__ f3, const float* __restrict__ ph3,
    float* __restrict__ x1, float* __restrict__ x2,
    int* __restrict__ bar, float* __restrict__ out, int K)
{
    __shared__ float v[12 * 256];        // 12 KB  current stage input
    __shared__ float ps[16 * 12 * 64];   // 48 KB  per-dgroup partials
    __shared__ float om[12 * 64];        // 3 KB   merged output tile
    __shared__ float mf[3][64];          //        modulation (pre-inverted)
    __shared__ unsigned pk[2048];        // 8 KB   packed (b,c,d,e)
    __shared__ unsigned hmap[2048];      // 8 KB   winner hash (this b)
    __shared__ unsigned wkc[2048];       // 8 KB   winner (d<<16)|(e<<8)|c
    __shared__ float wp1[2048];          // 8 KB   P1 at winner pos
    __shared__ int nwl;

    const int tid = (int)threadIdx.x;
    const int b  = (int)blockIdx.x >> 2;
    const int t  = (int)blockIdx.x & 3;
    const int e0 = t << 6;
    const int e2 = tid & 31;             // float2 lane: e = e0 + 2*e2 (+1)
    const int dg = tid >> 5;             // 0..15, 16 d per group

    // ---- init: pk staging, hash init, v=P2, modulation ----
    for (int k = tid; k < K; k += 512)
        pk[k] = ((unsigned)p5[k] << 24) | ((unsigned)p6[k] << 16) |
                ((unsigned)p7[k] << 8) | (unsigned)p8[k];
    for (int i = tid; i < 2048; i += 512) hmap[i] = 0xFFFFFFFFu;
    for (int i = tid; i < 3072; i += 512)
        v[i] = P2[(((i >> 8) * 6 + b) << 8) | (i & 255)];
    if (tid < 192) {
        int s = tid >> 6, j = tid & 63;
        float fr = (s == 0) ? f1[0]  : (s == 1) ? f2[0]  : f3[0];
        float ph = (s == 0) ? ph1[0] : (s == 1) ? ph2[0] : ph3[0];
        float sn = __sinf((float)(e0 + j) * TWO_PI * fr + ph);
        float mm = sn * sn * 0.1f + 0.95f;
        mf[s][j] = (s == 1) ? mm : 1.0f / mm;   // s0: /m, s1: *m, s2: /m
    }
    if (tid == 0) nwl = 0;
    __syncthreads();

    // ---- hash insert (this b only): last-write-wins = max k per (d,e) ----
    for (int k = tid; k < K; k += 512) {
        unsigned pv = pk[k];
        if ((pv >> 24) != (unsigned)b) continue;
        unsigned key = pv & 0xFFFFu;                 // (d<<8)|e
        unsigned mine = (key << 12) | (unsigned)k;   // k < 4096
        unsigned hh = (key * 2654435761u) >> 21;     // [0,2048)
        for (;;) {
            unsigned prev = atomicCAS(&hmap[hh], 0xFFFFFFFFu, mine);
            if (prev == 0xFFFFFFFFu) break;
            if ((prev >> 12) == key) { atomicMax(&hmap[hh], mine); break; }
            hh = (hh + 1) & 2047u;
        }
    }
    __syncthreads();

    // ---- winner readback -> compact LDS list (kept across stages) ----
    for (int k = tid; k < K; k += 512) {
        unsigned pv = pk[k];
        if ((pv >> 24) != (unsigned)b) continue;
        unsigned key = pv & 0xFFFFu;
        unsigned hh = (key * 2654435761u) >> 21;
        unsigned cur;
        for (;;) {
            cur = hmap[hh];
            if ((cur >> 12) == key) break;
            hh = (hh + 1) & 2047u;
        }
        if ((cur & 0xFFFu) == (unsigned)k) {         // last write wins
            unsigned c = (pv >> 16) & 0xFFu;
            int w = atomicAdd(&nwl, 1);
            wkc[w] = (key << 8) | c;                 // (d<<16)|(e<<8)|c
            wp1[w] = P1[(b << 16) | key];
        }
    }
    __syncthreads();
    const int nw = nwl;

    const float2* P1v = (const float2*)P1 + (b << 15) + (dg << 11) + (e0 >> 1) + e2;
    const float2* P3v = (const float2*)P3 + (b << 15) + (dg << 11) + (e0 >> 1) + e2;

    for (int s = 0; s < 3; ++s) {
        // ---- dense: stream tile once, 12 h accumulators ----
        float2 acc[12];
        #pragma unroll
        for (int h = 0; h < 12; ++h) acc[h] = make_float2(0.f, 0.f);
        #pragma unroll
        for (int dd = 0; dd < 16; ++dd) {
            float2 a = P1v[dd << 7];
            float2 p = P3v[dd << 7];
            float cx = fmaf(p.x, 0.975f, a.x);
            float cy = fmaf(p.y, 0.975f, a.y);
            const int d = (dg << 4) + dd;
            #pragma unroll
            for (int h = 0; h < 12; ++h) {
                float vv = v[(h << 8) | d];          // half-wave-uniform bcast
                acc[h].x = fmaf(vv, cx, acc[h].x);
                acc[h].y = fmaf(vv, cy, acc[h].y);
            }
        }
        #pragma unroll
        for (int h = 0; h < 12; ++h)
            *(float2*)&ps[((dg * 12 + h) << 6) + (e2 << 1)] = acc[h];
        __syncthreads();

        // ---- merge 16 -> 1 ----
        for (int idx = tid; idx < 768; idx += 512) {
            int h = idx >> 6, e = idx & 63;
            float sum = 0.f;
            #pragma unroll
            for (int g = 0; g < 16; ++g) sum += ps[((g * 12 + h) << 6) | e];
            om[idx] = sum;
        }
        __syncthreads();

        // ---- sparse corrections (in-tile winners) ----
        const float* Tt = (s == 0) ? T4 : (s == 1) ? T11 : T14;
        for (int i = tid; i < nw; i += 512) {
            unsigned wc = wkc[i];
            int e_w = (int)((wc >> 8) & 255u);
            if ((unsigned)(e_w - e0) >= 64u) continue;
            int d_w = (int)(wc >> 16);
            float val = Tt[(b << 8) | (wc & 255u)] - wp1[i];
            #pragma unroll
            for (int h = 0; h < 12; ++h)
                atomicAdd(&om[(h << 6) | (e_w - e0)],
                          v[(h << 8) | d_w] * val);
        }
        __syncthreads();

        // ---- modulate + store ----
        if (s == 2) {
            for (int idx = tid; idx < 768; idx += 512) {
                int h = idx >> 6, e = idx & 63;
                out[((h * 6 + b) << 8) | (e0 + e)] = om[idx] * mf[2][e];
            }
        } else {
            float* dst = (s == 0) ? x1 : x2;
            for (int idx = tid; idx < 768; idx += 512) {
                int h = idx >> 6, e = idx & 63;
                // relaxed agent store: sc0 sc1, straight to coherent LLC
                __hip_atomic_store(&dst[((h * 6 + b) << 8) | (e0 + e)],
                                   om[idx] * mf[s][e],
                                   __ATOMIC_RELAXED, __HIP_MEMORY_SCOPE_AGENT);
            }
            // __syncthreads drains vmcnt(0) for ALL waves' stores before any
            // thread proceeds -> stores are LLC-visible before bar increment.
            __syncthreads();
            if (tid == 0) {
                __hip_atomic_fetch_add(&bar[s], 1, __ATOMIC_RELAXED,
                                       __HIP_MEMORY_SCOPE_AGENT);
                while (__hip_atomic_load(&bar[s], __ATOMIC_RELAXED,
                                         __HIP_MEMORY_SCOPE_AGENT) < 24)
                    __builtin_amdgcn_s_sleep(1);
            }
            __syncthreads();
            // reload v through the LLC (relaxed agent loads bypass stale L1/L2)
            float* src = dst;
            for (int i = tid; i < 3072; i += 512)
                v[i] = __hip_atomic_load(
                    &src[(((i >> 8) * 6 + b) << 8) | (i & 255)],
                    __ATOMIC_RELAXED, __HIP_MEMORY_SCOPE_AGENT);
            __syncthreads();
        }
    }
}

extern "C" void kernel_launch(void* const* d_in, const int* in_sizes, int n_in,
                              void* d_out, int out_size, void* d_ws, size_t ws_size,
                              hipStream_t stream)
{
    (void)n_in; (void)out_size; (void)ws_size;
    const float* P1  = (const float*)d_in[0];
    const float* P2  = (const float*)d_in[1];
    const float* P3  = (const float*)d_in[2];
    const float* T4  = (const float*)d_in[3];
    const int*   p5  = (const int*)d_in[4];
    const int*   p6  = (const int*)d_in[5];
    const int*   p7  = (const int*)d_in[6];
    const int*   p8  = (const int*)d_in[7];
    const float* f1  = (const float*)d_in[8];
    const float* ph1 = (const float*)d_in[9];
    const float* T11 = (const float*)d_in[10];
    const float* f2  = (const float*)d_in[11];
    const float* ph2 = (const float*)d_in[12];
    const float* T14 = (const float*)d_in[13];
    const float* f3  = (const float*)d_in[14];
    const float* ph3 = (const float*)d_in[15];
    float* out = (float*)d_out;
    int K = in_sizes[4];

    char* ws = (char*)d_ws;
    float* x1  = (float*)(ws);
    float* x2  = (float*)(ws + 73728);
    int*   bar = (int*)  (ws + 147456);

    // zero the barrier counters every call (captured as a memset node)
    hipMemsetAsync(bar, 0, 64, stream);
    hipLaunchKernelGGL(fused_all, dim3(24), dim3(512), 0, stream,
                       P1, P2, P3, T4, p5, p6, p7, p8,
                       f1, ph1, T11, f2, ph2, T14, f3, ph3,
                       x1, x2, bar, out, K);
}

// Round 11
// 20.074 us; speedup vs baseline: 2.3793x; 1.7527x over previous
//
#include <hip/hip_runtime.h>

#define TWO_PI 6.2831853071795864769f

// ONE dispatch, NO barriers, NO ws. Grid = 96 blocks, blk = h*8 + b:
// blk % 8 = b => the 12 h-chains of batch b all land on XCD b (round-robin
// workgroup->XCD dispatch), so P1_b/P3_b (512 KB) is fetched ONCE into that
// XCD's 4MB L2 and shared by all 12 blocks. This attacks the measured
// per-CU private-ingest wall (~10 B/cyc/CU) that pinned r3-r7 at ~23us:
// same bytes per CU, but now served at L2-hit bandwidth (~32-48 B/cyc/CU).
// Blocks with b >= 6 exit immediately (24 idle slots).
//
// Per block: thread=(dg 0..15, eg 0..63) register-caches
// m4[i] = (P1 + 0.975*P3)[b][dg*16+i][eg*4..+3]. Scatter handled as sparse
// corrections (val_s - P1[pos]) at last-write-wins winners, resolved
// per-block by a direct LDS hash over all K (key=(d,e), payload=k,
// atomicMax = np last-write-wins). 3 chained stages private to the block.
__global__ __launch_bounds__(1024, 4) void fused_chain(
    const float* __restrict__ P1, const float* __restrict__ P2,
    const float* __restrict__ P3, const float* __restrict__ T4,
    const int* __restrict__ p5, const int* __restrict__ p6,
    const int* __restrict__ p7, const int* __restrict__ p8,
    const float* __restrict__ f1, const float* __restrict__ ph1,
    const float* __restrict__ T11, const float* __restrict__ f2,
    const float* __restrict__ ph2, const float* __restrict__ T14,
    const float* __restrict__ f3, const float* __restrict__ ph3,
    float* __restrict__ out, int K)
{
    const int blk = (int)blockIdx.x;
    const int b = blk & 7;               // = blk % 8 = XCD id
    if (b >= 6) return;
    const int h = blk >> 3;              // 0..11

    __shared__ float v[256];
    __shared__ float pv[16][256];          // 16 KB partials
    __shared__ float modl[3][256];
    __shared__ unsigned hmap[4096];        // (key<<12)|k ; empty=0xFFFFFFFF
    __shared__ unsigned short wde[2048];   // winner (d<<8)|e
    __shared__ float wv0[2048], wv1[2048], wv2[2048];
    __shared__ int nw;

    const int tid = (int)threadIdx.x;
    const int dg = tid >> 6;               // 0..15
    const int eg = tid & 63;               // 0..63

    // ---- phase 1: issue dense m loads FIRST (latency hides under hash) ----
    const float4* P1v = (const float4*)P1;
    const float4* P3v = (const float4*)P3;
    const int rbase = (b << 8) + (dg << 4);
    float4 m4[16];
    #pragma unroll
    for (int i = 0; i < 16; ++i) {
        float4 a = P1v[(rbase + i) * 64 + eg];
        float4 c = P3v[(rbase + i) * 64 + eg];
        m4[i].x = fmaf(c.x, 0.975f, a.x);
        m4[i].y = fmaf(c.y, 0.975f, a.y);
        m4[i].z = fmaf(c.z, 0.975f, a.z);
        m4[i].w = fmaf(c.w, 0.975f, a.w);
    }

    // ---- small init (overlaps with loads) ----
    if (tid < 256) v[tid] = P2[(h * 6 + b) * 256 + tid];
    if (tid < 768) {
        int s = tid >> 8, ee = tid & 255;
        float fr = (s == 0) ? f1[0]  : (s == 1) ? f2[0]  : f3[0];
        float ph = (s == 0) ? ph1[0] : (s == 1) ? ph2[0] : ph3[0];
        float sn = __sinf((float)ee * TWO_PI * fr + ph);
        float mm = sn * sn * 0.1f + 0.95f;
        modl[s][ee] = (s == 1) ? mm : 1.0f / mm;   // s0: /m, s1: *m, s2: /m
    }
    for (int i = tid; i < 4096; i += 1024) hmap[i] = 0xFFFFFFFFu;
    if (tid == 0) nw = 0;
    __syncthreads();

    // ---- phase 2: direct hash insert, last-write-wins = max k per (d,e) ----
    for (int k = tid; k < K; k += 1024) {
        if (p5[k] != b) continue;
        unsigned key = ((unsigned)p7[k] << 8) | (unsigned)p8[k];   // 16 bits
        unsigned mine = (key << 12) | (unsigned)k;                 // k < 4096
        unsigned hh = (key * 2654435761u) >> 20;                   // [0,4096)
        for (;;) {
            unsigned prev = atomicCAS(&hmap[hh], 0xFFFFFFFFu, mine);
            if (prev == 0xFFFFFFFFu) break;
            if ((prev >> 12) == key) { atomicMax(&hmap[hh], mine); break; }
            hh = (hh + 1) & 4095u;
        }
    }
    __syncthreads();

    // ---- phase 3: winner readback -> sparse corrections ----
    for (int k = tid; k < K; k += 1024) {
        if (p5[k] != b) continue;
        unsigned key = ((unsigned)p7[k] << 8) | (unsigned)p8[k];
        unsigned hh = (key * 2654435761u) >> 20;
        unsigned cur;
        for (;;) {
            cur = hmap[hh];
            if ((cur >> 12) == key) break;
            hh = (hh + 1) & 4095u;
        }
        if ((cur & 0xFFFu) == (unsigned)k) {        // winner (last write)
            int c = p6[k];
            float p1v = P1[(b << 16) | key];        // b*65536 + d*256 + e
            int w = atomicAdd(&nw, 1);
            wde[w] = (unsigned short)key;
            wv0[w] = T4 [b * 256 + c] - p1v;
            wv1[w] = T11[b * 256 + c] - p1v;
            wv2[w] = T14[b * 256 + c] - p1v;
        }
    }
    __syncthreads();
    const int nwl = nw;

    // ---- phase 4: three chained stages ----
    const int e256 = tid & 255;
    for (int s = 0; s < 3; ++s) {
        float4 acc = make_float4(0.f, 0.f, 0.f, 0.f);
        #pragma unroll
        for (int j = 0; j < 4; ++j) {
            float4 vv = *(const float4*)&v[(dg << 4) + (j << 2)];
            float4 m0 = m4[(j << 2) + 0];
            float4 m1 = m4[(j << 2) + 1];
            float4 m2 = m4[(j << 2) + 2];
            float4 m3 = m4[(j << 2) + 3];
            acc.x = fmaf(vv.x, m0.x, acc.x); acc.y = fmaf(vv.x, m0.y, acc.y);
            acc.z = fmaf(vv.x, m0.z, acc.z); acc.w = fmaf(vv.x, m0.w, acc.w);
            acc.x = fmaf(vv.y, m1.x, acc.x); acc.y = fmaf(vv.y, m1.y, acc.y);
            acc.z = fmaf(vv.y, m1.z, acc.z); acc.w = fmaf(vv.y, m1.w, acc.w);
            acc.x = fmaf(vv.z, m2.x, acc.x); acc.y = fmaf(vv.z, m2.y, acc.y);
            acc.z = fmaf(vv.z, m2.z, acc.z); acc.w = fmaf(vv.z, m2.w, acc.w);
            acc.x = fmaf(vv.w, m3.x, acc.x); acc.y = fmaf(vv.w, m3.y, acc.y);
            acc.z = fmaf(vv.w, m3.z, acc.z); acc.w = fmaf(vv.w, m3.w, acc.w);
        }
        *(float4*)&pv[dg][eg << 2] = acc;
        __syncthreads();
        {   // reduce 16 -> 4 rows
            int r = tid >> 8;                       // 0..3
            float x = pv[r][e256] + pv[r + 4][e256] +
                      pv[r + 8][e256] + pv[r + 12][e256];
            __syncthreads();
            pv[r][e256] = x;
        }
        __syncthreads();
        if (tid < 256)                              // reduce 4 -> 1
            pv[0][tid] = (pv[0][tid] + pv[1][tid]) + (pv[2][tid] + pv[3][tid]);
        __syncthreads();
        const float* wvs = (s == 0) ? wv0 : (s == 1) ? wv1 : wv2;
        for (int i = tid; i < nwl; i += 1024) {
            unsigned de = wde[i];
            atomicAdd(&pv[0][de & 255u], v[de >> 8] * wvs[i]);
        }
        __syncthreads();
        if (tid < 256)
            v[tid] = pv[0][tid] * modl[s][tid];
        __syncthreads();
    }
    if (tid < 256) out[(h * 6 + b) * 256 + tid] = v[tid];
}

extern "C" void kernel_launch(void* const* d_in, const int* in_sizes, int n_in,
                              void* d_out, int out_size, void* d_ws, size_t ws_size,
                              hipStream_t stream)
{
    (void)n_in; (void)out_size; (void)d_ws; (void)ws_size;
    const float* P1  = (const float*)d_in[0];
    const float* P2  = (const float*)d_in[1];
    const float* P3  = (const float*)d_in[2];
    const float* T4  = (const float*)d_in[3];
    const int*   p5  = (const int*)d_in[4];
    const int*   p6  = (const int*)d_in[5];
    const int*   p7  = (const int*)d_in[6];
    const int*   p8  = (const int*)d_in[7];
    const float* f1  = (const float*)d_in[8];
    const float* ph1 = (const float*)d_in[9];
    const float* T11 = (const float*)d_in[10];
    const float* f2  = (const float*)d_in[11];
    const float* ph2 = (const float*)d_in[12];
    const float* T14 = (const float*)d_in[13];
    const float* f3  = (const float*)d_in[14];
    const float* ph3 = (const float*)d_in[15];
    float* out = (float*)d_out;
    int K = in_sizes[4];

    hipLaunchKernelGGL(fused_chain, dim3(96), dim3(1024), 0, stream,
                       P1, P2, P3, T4, p5, p6, p7, p8,
                       f1, ph1, T11, f2, ph2, T14, f3, ph3, out, K);
}